// Round 5
// baseline (837.083 us; speedup 1.0000x reference)
//
#include <hip/hip_runtime.h>
#include <math.h>

// Problem constants
#define Bn 64
#define Cn 256
#define Tn 4096
#define On 256
#define TT 64        // t-tile per compute step
#define NTILE 64     // Tn/TT
#define NROW 16384   // Bn*On

typedef float f32x4 __attribute__((ext_vector_type(4)));
typedef __bf16 bf16x8 __attribute__((ext_vector_type(8)));
typedef __bf16 bf16x4v __attribute__((ext_vector_type(4)));
typedef unsigned short u16;
typedef u16 u16x8 __attribute__((ext_vector_type(8)));

static __device__ __forceinline__ float rcpf(float x) { return __builtin_amdgcn_rcpf(x); }
static __device__ __forceinline__ float bf2f(u16 u) { return __uint_as_float(((unsigned)u) << 16); }

#if __has_builtin(__builtin_amdgcn_exp2f)
#define EXP2(x) __builtin_amdgcn_exp2f(x)
#else
#define EXP2(x) exp2f(x)
#endif

// LDS-only barrier: no vmcnt(0) drain.
#define BAR() do { asm volatile("s_waitcnt lgkmcnt(0)" ::: "memory"); \
                   __builtin_amdgcn_s_barrier(); } while (0)

// log2(e) folding scales
#define SC_TANH -2.8853900817779268f   // -2*log2(e): E1 = exp2(Wt'x+bt') = e^{-2v}
#define SC_SIGM -1.4426950408889634f   // -log2(e):   E2 = e^{-s}
#define SC_W     1.4426950408889634f   // +log2(e):   p  = exp2(z') = e^{z}

// ---------------------------------------------------------------------------
// Kernel 0: weights f32 -> bf16, A-fragment order, with exp2 folding scales.
// ---------------------------------------------------------------------------
__global__ void wprep_k(const float* __restrict__ Wt, const float* __restrict__ Ws,
                        const float* __restrict__ Ww, const float* __restrict__ Wf,
                        u16* __restrict__ dst) {
  int gid = blockIdx.x * 256 + threadIdx.x;     // 0 .. 4*65536-1
  int w = gid >> 16, rem = gid & 65535;
  int frag = rem >> 9, lane = (rem >> 3) & 63, i = rem & 7;
  int ot = frag >> 3, kt = frag & 7;
  int row = ot * 16 + (lane & 15);
  int col = kt * 32 + ((lane >> 4) << 3) + i;
  const float* W = (w == 0) ? Wt : (w == 1) ? Ws : (w == 2) ? Ww : Wf;
  float sc = (w == 0) ? SC_TANH : (w == 1) ? SC_SIGM : (w == 2) ? SC_W : 1.0f;
  __bf16 h = (__bf16)(W[row * 256 + col] * sc);
  dst[gid] = *(u16*)&h;
}

// ---------------------------------------------------------------------------
// Pass 1 (persistent 2-tile blocks, async-STAGE split in the LOW-pressure
// window). Per tile: [issue next-tile loads -> st regs] F-loop -> F-epi ->
// [st -> ds_write xbufB] -> T,S-loop -> BAR -> g-epi in-place -> BAR ->
// Z-loop -> Z-epi. st(+32 regs) overlaps only accF(32), never accT+accS(64):
// peak ~100 VGPR, no spill (R4's spill was STAGE at the 64-acc peak).
// LDS = 2x32KB + 4KB = 68KB -> 2 blocks/CU, 4 waves/SIMD.
// ---------------------------------------------------------------------------
__global__ __launch_bounds__(512, 4) void pass1_k(
    const float* __restrict__ x, const int* __restrict__ lens, const int* __restrict__ levels,
    const u16* __restrict__ wtF, const u16* __restrict__ wsF, const u16* __restrict__ wwF,
    const u16* __restrict__ wfF,
    const float* __restrict__ btp, const float* __restrict__ bsp, const float* __restrict__ bwp,
    const float* __restrict__ bfp,
    u16* __restrict__ pW, u16* __restrict__ fW,
    float* __restrict__ Sp) {
  __shared__ u16 xbufA[16384];   // 32 KB
  __shared__ u16 xbufB[16384];   // 32 KB
  __shared__ float bt_sh[256], bs_sh[256], bw_sh[256], bf_sh[256];

  int pair = blockIdx.x, b = blockIdx.y;
  int tile0 = pair * 2;
  int t0 = tile0 * TT;
  int tid = threadIdx.x, wid = tid >> 6, lane = tid & 63;
  int kb = lens[b] >> (levels[0] - 1);

  if (t0 >= kb) {  // both tiles fully masked: zero partials only
    if (tid < 256) {
      Sp[(size_t)tile0 * NROW + b * 256 + tid] = 0.f;
      Sp[(size_t)(tile0 + 1) * NROW + b * 256 + tid] = 0.f;
    }
    return;
  }
  bool valid1 = (t0 + TT) < kb;

  if (tid < 256) {
    bt_sh[tid] = btp[tid] * SC_TANH;
    bs_sh[tid] = bsp[tid] * SC_SIGM;
    bw_sh[tid] = bwp[tid] * SC_W;
    bf_sh[tid] = bfp[tid];
  }

  // prologue: stage tile0 into xbufA (serial; nothing to hide under)
  {
    const float* xbS = x + (size_t)b * Cn * Tn + t0;
    #pragma unroll
    for (int it = 0; it < 8; ++it) {
      int cb = (wid + 8 * it) * 4;
      float v0 = __builtin_nontemporal_load(&xbS[(size_t)(cb + 0) * Tn + lane]);
      float v1 = __builtin_nontemporal_load(&xbS[(size_t)(cb + 1) * Tn + lane]);
      float v2 = __builtin_nontemporal_load(&xbS[(size_t)(cb + 2) * Tn + lane]);
      float v3 = __builtin_nontemporal_load(&xbS[(size_t)(cb + 3) * Tn + lane]);
      bf16x4v pk = { (__bf16)v0, (__bf16)v1, (__bf16)v2, (__bf16)v3 };
      int frag = ((cb >> 5) * 4 + (lane >> 4));
      int lfr  = ((cb >> 3) & 3) * 16 + (lane & 15);
      *(bf16x4v*)&xbufA[(frag << 9) + (lfr << 3) + (cb & 7)] = pk;
    }
  }
  BAR();

  for (int half = 0; half < 2; ++half) {
    u16* xb_cur = half ? xbufB : xbufA;       // x of this tile; becomes g
    int t0h = t0 + half * TT;
    int tileh = tile0 + half;
    bool do_pf = (half == 0) && valid1;

    // ---- issue next-tile loads EARLY (low-pressure window: only accF live) ----
    float st[32];
    if (do_pf) {
      const float* xbS = x + (size_t)b * Cn * Tn + (t0 + TT);
      #pragma unroll
      for (int it = 0; it < 8; ++it) {
        int cb = (wid + 8 * it) * 4;
        st[it * 4 + 0] = __builtin_nontemporal_load(&xbS[(size_t)(cb + 0) * Tn + lane]);
        st[it * 4 + 1] = __builtin_nontemporal_load(&xbS[(size_t)(cb + 1) * Tn + lane]);
        st[it * 4 + 2] = __builtin_nontemporal_load(&xbS[(size_t)(cb + 2) * Tn + lane]);
        st[it * 4 + 3] = __builtin_nontemporal_load(&xbS[(size_t)(cb + 3) * Tn + lane]);
      }
    }

    // ---- loop F: fv = Wf x + bf (acc dies at F-epi; st in flight above) ----
    {
      f32x4 accF[2][4];
      #pragma unroll
      for (int j = 0; j < 2; ++j)
        #pragma unroll
        for (int n = 0; n < 4; ++n) accF[j][n] = (f32x4)0.f;
      #pragma unroll
      for (int kt = 0; kt < 8; ++kt) {
        bf16x8 bb[4];
        #pragma unroll
        for (int n = 0; n < 4; ++n)
          bb[n] = *(const bf16x8*)&xb_cur[((kt * 4 + n) << 9) + (lane << 3)];
        #pragma unroll
        for (int j = 0; j < 2; ++j) {
          bf16x8 af = *(const bf16x8*)&wfF[((wid * 2 + j) * 8 + kt) * 512 + lane * 8];
          #pragma unroll
          for (int n = 0; n < 4; ++n)
            accF[j][n] = __builtin_amdgcn_mfma_f32_16x16x32_bf16(af, bb[n], accF[j][n], 0, 0, 0);
        }
      }
      #pragma unroll
      for (int j = 0; j < 2; ++j) {
        int rowbase = (wid * 2 + j) * 16 + ((lane >> 4) << 2);
        int oq = rowbase >> 2;
        size_t tbase = ((size_t)(b * 64 + oq)) * Tn + t0h + (lane & 15);
        #pragma unroll
        for (int n = 0; n < 4; ++n) {
          bf16x4v ff;
          #pragma unroll
          for (int r = 0; r < 4; ++r) ff[r] = (__bf16)(accF[j][n][r] + bf_sh[rowbase + r]);
          *(bf16x4v*)&fW[(tbase + n * 16) * 4] = ff;
        }
      }
    }

    // ---- write staged next tile to xbufB (st dies HERE, before T,S peak) ----
    if (do_pf) {
      #pragma unroll
      for (int it = 0; it < 8; ++it) {
        int cb = (wid + 8 * it) * 4;
        bf16x4v pk = { (__bf16)st[it * 4 + 0], (__bf16)st[it * 4 + 1],
                       (__bf16)st[it * 4 + 2], (__bf16)st[it * 4 + 3] };
        int frag = ((cb >> 5) * 4 + (lane >> 4));
        int lfr  = ((cb >> 3) & 3) * 16 + (lane & 15);
        *(bf16x4v*)&xbufB[(frag << 9) + (lfr << 3) + (cb & 7)] = pk;
      }
    }

    // ---- T,S fused loop (accT/accS live until g-epi; st dead) ----
    f32x4 accT[2][4], accS[2][4];
    #pragma unroll
    for (int j = 0; j < 2; ++j)
      #pragma unroll
      for (int n = 0; n < 4; ++n) { accT[j][n] = (f32x4)0.f; accS[j][n] = (f32x4)0.f; }
    #pragma unroll
    for (int kt = 0; kt < 8; ++kt) {
      bf16x8 bb[4];
      #pragma unroll
      for (int n = 0; n < 4; ++n)
        bb[n] = *(const bf16x8*)&xb_cur[((kt * 4 + n) << 9) + (lane << 3)];
      #pragma unroll
      for (int j = 0; j < 2; ++j) {
        bf16x8 at  = *(const bf16x8*)&wtF[((wid * 2 + j) * 8 + kt) * 512 + lane * 8];
        bf16x8 as2 = *(const bf16x8*)&wsF[((wid * 2 + j) * 8 + kt) * 512 + lane * 8];
        #pragma unroll
        for (int n = 0; n < 4; ++n) {
          accT[j][n] = __builtin_amdgcn_mfma_f32_16x16x32_bf16(at,  bb[n], accT[j][n], 0, 0, 0);
          accS[j][n] = __builtin_amdgcn_mfma_f32_16x16x32_bf16(as2, bb[n], accS[j][n], 0, 0, 0);
        }
      }
    }

    BAR();   // all waves done reading xb_cur (F and T,S); xbufB writes drained

    // ---- g-epi: g = (1-E1)/((1+E1)(1+E2)) overwrites xb_cur in-place ----
    #pragma unroll
    for (int j = 0; j < 2; ++j) {
      int rowbase = (wid * 2 + j) * 16 + ((lane >> 4) << 2);
      #pragma unroll
      for (int n = 0; n < 4; ++n) {
        bf16x4v pk;
        #pragma unroll
        for (int r = 0; r < 4; ++r) {
          float e1 = EXP2(accT[j][n][r] + bt_sh[rowbase + r]);
          float e2 = EXP2(accS[j][n][r] + bs_sh[rowbase + r]);
          pk[r] = (__bf16)((1.f - e1) * rcpf((1.f + e1) * (1.f + e2)));
        }
        int frag = ((rowbase >> 5) * 4 + n);
        int lfr  = ((rowbase >> 3) & 3) * 16 + (lane & 15);
        *(bf16x4v*)&xb_cur[(frag << 9) + (lfr << 3) + (rowbase & 7)] = pk;
      }
    }
    BAR();   // g visible to all waves

    // ---- loop Z: z' = Ww' g + bw' ----
    f32x4 accZ[2][4];
    #pragma unroll
    for (int j = 0; j < 2; ++j)
      #pragma unroll
      for (int n = 0; n < 4; ++n) accZ[j][n] = (f32x4)0.f;
    #pragma unroll
    for (int kt = 0; kt < 8; ++kt) {
      bf16x8 gg[4];
      #pragma unroll
      for (int n = 0; n < 4; ++n)
        gg[n] = *(const bf16x8*)&xb_cur[((kt * 4 + n) << 9) + (lane << 3)];
      #pragma unroll
      for (int j = 0; j < 2; ++j) {
        bf16x8 aw = *(const bf16x8*)&wwF[((wid * 2 + j) * 8 + kt) * 512 + lane * 8];
        #pragma unroll
        for (int n = 0; n < 4; ++n)
          accZ[j][n] = __builtin_amdgcn_mfma_f32_16x16x32_bf16(aw, gg[n], accZ[j][n], 0, 0, 0);
      }
    }

    // ---- Z-epi: p = exp2(z') masked, quad stores, Sp partials ----
    #pragma unroll
    for (int j = 0; j < 2; ++j) {
      int rowbase = (wid * 2 + j) * 16 + ((lane >> 4) << 2);
      int oq = rowbase >> 2;
      size_t tbase = ((size_t)(b * 64 + oq)) * Tn + t0h + (lane & 15);
      float s[4] = {0.f, 0.f, 0.f, 0.f};
      #pragma unroll
      for (int n = 0; n < 4; ++n) {
        bool v = (t0h + n * 16 + (lane & 15)) < kb;
        bf16x4v pp;
        #pragma unroll
        for (int r = 0; r < 4; ++r) {
          float z = accZ[j][n][r] + bw_sh[rowbase + r];
          float p = v ? EXP2(z) : 0.f;    // |z'| <= ~17: safe
          s[r] += p;
          pp[r] = (__bf16)p;
        }
        *(bf16x4v*)&pW[(tbase + n * 16) * 4] = pp;
      }
      #pragma unroll
      for (int off = 1; off < 16; off <<= 1)
        #pragma unroll
        for (int r = 0; r < 4; ++r) s[r] += __shfl_xor(s[r], off, 64);
      if ((lane & 15) == 0) {
        #pragma unroll
        for (int r = 0; r < 4; ++r)
          Sp[(size_t)tileh * NROW + b * 256 + rowbase + r] = s[r];
      }
    }

    if (half == 0 && !valid1) {   // tile1 fully masked: zero its partials, done
      if (tid < 256) Sp[(size_t)(tile0 + 1) * NROW + b * 256 + tid] = 0.f;
      return;
    }
  }
}

// ---------------------------------------------------------------------------
// Pass 2: one block per (b, o-quad). a = p/D, a2 = a*fv, out = sum a2.
// ---------------------------------------------------------------------------
__global__ __launch_bounds__(256) void pass2_k(
    const int* __restrict__ lens, const int* __restrict__ levels,
    const u16* __restrict__ pW, const u16* __restrict__ fW,
    const float* __restrict__ Sp,
    float* __restrict__ out0, float* __restrict__ aOut, float* __restrict__ a2Out) {
  int b = blockIdx.y, oq = blockIdx.x;
  int kb = lens[b] >> (levels[0] - 1);
  int tid = threadIdx.x, wid = tid >> 6, lane = tid & 63;
  __shared__ float dsh[16];
  __shared__ float obuf[16];

  // D for the 4 rows: tid -> (tile = tid>>2, r = tid&3)
  float v = Sp[(size_t)(tid >> 2) * NROW + b * 256 + oq * 4 + (tid & 3)];
  #pragma unroll
  for (int off = 4; off < 64; off <<= 1) v += __shfl_xor(v, off, 64);
  if (lane < 4) dsh[wid * 4 + lane] = v;
  __syncthreads();
  float scr[4];
  #pragma unroll
  for (int r = 0; r < 4; ++r)
    scr[r] = 1.f / (dsh[r] + dsh[4 + r] + dsh[8 + r] + dsh[12 + r]);

  size_t pbase = ((size_t)(b * 64 + oq)) * Tn;        // in t units; elem idx = (pbase+t)*4
  size_t obase0 = ((size_t)(b * 256 + oq * 4)) * Tn;  // row 0 of the quad
  float osum[4] = {0.f, 0.f, 0.f, 0.f};

  #pragma unroll
  for (int c = 0; c < 4; ++c) {
    int t = c * 1024 + tid * 4;
    if (t < kb) {
      u16x8 pa = *(const u16x8*)&pW[(pbase + t) * 4];      // t, t+1
      u16x8 pb = *(const u16x8*)&pW[(pbase + t) * 4 + 8];  // t+2, t+3
      u16x8 fa = *(const u16x8*)&fW[(pbase + t) * 4];
      u16x8 fb = *(const u16x8*)&fW[(pbase + t) * 4 + 8];
      bool v1 = (t + 1) < kb, v2 = (t + 2) < kb, v3 = (t + 3) < kb;
      #pragma unroll
      for (int r = 0; r < 4; ++r) {
        float a0 = bf2f(pa[r]) * scr[r];
        float a1 = v1 ? bf2f(pa[4 + r]) * scr[r] : 0.f;
        float a2_ = v2 ? bf2f(pb[r]) * scr[r] : 0.f;
        float a3 = v3 ? bf2f(pb[4 + r]) * scr[r] : 0.f;
        f32x4 av = { a0, a1, a2_, a3 };
        f32x4 a2v = { a0 * bf2f(fa[r]), a1 * bf2f(fa[4 + r]),
                      a2_ * bf2f(fb[r]), a3 * bf2f(fb[4 + r]) };
        osum[r] += a2v[0] + a2v[1] + a2v[2] + a2v[3];
        __builtin_nontemporal_store(av,  (f32x4*)&aOut[obase0 + (size_t)r * Tn + t]);
        __builtin_nontemporal_store(a2v, (f32x4*)&a2Out[obase0 + (size_t)r * Tn + t]);
      }
    } else {
      f32x4 z4 = (f32x4)0.f;
      #pragma unroll
      for (int r = 0; r < 4; ++r) {
        __builtin_nontemporal_store(z4, (f32x4*)&aOut[obase0 + (size_t)r * Tn + t]);
        __builtin_nontemporal_store(z4, (f32x4*)&a2Out[obase0 + (size_t)r * Tn + t]);
      }
    }
  }

  // out0: per-wave shuffle reduce each row, then cross-wave via LDS
  #pragma unroll
  for (int r = 0; r < 4; ++r) {
    float s = osum[r];
    #pragma unroll
    for (int off = 1; off < 64; off <<= 1) s += __shfl_xor(s, off, 64);
    if (lane == 0) obuf[wid * 4 + r] = s;
  }
  __syncthreads();
  if (tid < 4)
    out0[b * 256 + oq * 4 + tid] = obuf[tid] + obuf[4 + tid] + obuf[8 + tid] + obuf[12 + tid];
}

// ---------------------------------------------------------------------------
extern "C" void kernel_launch(void* const* d_in, const int* in_sizes, int n_in,
                              void* d_out, int out_size, void* d_ws, size_t ws_size,
                              hipStream_t stream) {
  const float* x    = (const float*)d_in[0];
  const int*   lens = (const int*)d_in[1];
  const int*   lev  = (const int*)d_in[2];
  const float* Wt = (const float*)d_in[3];
  const float* bt = (const float*)d_in[4];
  const float* Ws = (const float*)d_in[5];
  const float* bs = (const float*)d_in[6];
  const float* Ww = (const float*)d_in[7];
  const float* bw = (const float*)d_in[8];
  const float* Wf = (const float*)d_in[9];
  const float* bf = (const float*)d_in[10];

  u16* wsu = (u16*)d_ws;
  u16* wtF = wsu;                 // 4 x 65536 u16 = 512 KB
  u16* wsF = wsu + 65536;
  u16* wwF = wsu + 131072;
  u16* wfF = wsu + 196608;
  u16* pW  = wsu + 262144;        // [b][oq][t][4] bf16 = 134 MB
  u16* fW  = pW + (size_t)NROW * Tn;
  float* Sp = (float*)(fW + (size_t)NROW * Tn);  // [NTILE][NROW] = 4 MB

  float* out0  = (float*)d_out;
  float* aOut  = out0 + Bn * On;
  float* a2Out = aOut + (size_t)Bn * On * Tn;

  wprep_k<<<1024, 256, 0, stream>>>(Wt, Ws, Ww, Wf, wsu);
  pass1_k<<<dim3(NTILE / 2, Bn), 512, 0, stream>>>(x, lens, lev, wtF, wsF, wwF, wfF,
                                                   bt, bs, bw, bf, pW, fW, Sp);
  pass2_k<<<dim3(64, Bn), 256, 0, stream>>>(lens, lev, pW, fW, Sp, out0, aOut, a2Out);
}

// Round 6
// 258.571 us; speedup vs baseline: 3.2373x; 3.2373x over previous
//
#include <hip/hip_runtime.h>
#include <math.h>

// Problem constants
#define Bn 64
#define Cn 256
#define Tn 4096
#define On 256
#define TT 64        // t-tile per block
#define NTILE 64     // Tn/TT
#define NROW 16384   // Bn*On

typedef float f32x4 __attribute__((ext_vector_type(4)));
typedef __bf16 bf16x8 __attribute__((ext_vector_type(8)));
typedef __bf16 bf16x4v __attribute__((ext_vector_type(4)));
typedef unsigned short u16;
typedef u16 u16x8 __attribute__((ext_vector_type(8)));

static __device__ __forceinline__ float rcpf(float x) { return __builtin_amdgcn_rcpf(x); }
static __device__ __forceinline__ float bf2f(u16 u) { return __uint_as_float(((unsigned)u) << 16); }

#if __has_builtin(__builtin_amdgcn_exp2f)
#define EXP2(x) __builtin_amdgcn_exp2f(x)
#else
#define EXP2(x) exp2f(x)
#endif

// LDS-only barrier: no vmcnt(0) drain.
#define BAR() do { asm volatile("s_waitcnt lgkmcnt(0)" ::: "memory"); \
                   __builtin_amdgcn_s_barrier(); } while (0)

// log2(e) folding scales
#define SC_TANH -2.8853900817779268f   // -2*log2(e): E1 = exp2(Wt'x+bt') = e^{-2v}
#define SC_SIGM -1.4426950408889634f   // -log2(e):   E2 = e^{-s}
#define SC_W     1.4426950408889634f   // +log2(e):   p  = exp2(z') = e^{z}

// ---------------------------------------------------------------------------
// Kernel 0: weights f32 -> bf16, A-fragment order, with exp2 folding scales.
// ---------------------------------------------------------------------------
__global__ void wprep_k(const float* __restrict__ Wt, const float* __restrict__ Ws,
                        const float* __restrict__ Ww, const float* __restrict__ Wf,
                        u16* __restrict__ dst) {
  int gid = blockIdx.x * 256 + threadIdx.x;     // 0 .. 4*65536-1
  int w = gid >> 16, rem = gid & 65535;
  int frag = rem >> 9, lane = (rem >> 3) & 63, i = rem & 7;
  int ot = frag >> 3, kt = frag & 7;
  int row = ot * 16 + (lane & 15);
  int col = kt * 32 + ((lane >> 4) << 3) + i;
  const float* W = (w == 0) ? Wt : (w == 1) ? Ws : (w == 2) ? Ww : Wf;
  float sc = (w == 0) ? SC_TANH : (w == 1) ? SC_SIGM : (w == 2) ? SC_W : 1.0f;
  __bf16 h = (__bf16)(W[row * 256 + col] * sc);
  dst[gid] = *(u16*)&h;
}

// ---------------------------------------------------------------------------
// Pass 1 (R2 structure + F-before-barrier reorder):
//   stage x -> BAR -> [T,S GEMM] -> g-epi (g_lds) -> [F GEMM reads x_lds]
//   -> F-epi (fW) -> BAR -> [Z GEMM reads g_lds] -> Z-epi (pW, Sp).
// F depends only on x, so it executes between the g-epi ds_writes and the
// barrier, absorbing wave skew + g-write latency that R2 exposed at BAR2.
// No new live ranges: peak pressure = T,S loop (same as R2). 8 waves x
// 2 o-tiles, 68 KB LDS -> 2 blocks/CU, 4 waves/SIMD.
// ---------------------------------------------------------------------------
__global__ __launch_bounds__(512, 4) void pass1_k(
    const float* __restrict__ x, const int* __restrict__ lens, const int* __restrict__ levels,
    const u16* __restrict__ wtF, const u16* __restrict__ wsF, const u16* __restrict__ wwF,
    const u16* __restrict__ wfF,
    const float* __restrict__ btp, const float* __restrict__ bsp, const float* __restrict__ bwp,
    const float* __restrict__ bfp,
    u16* __restrict__ pW, u16* __restrict__ fW,
    float* __restrict__ Sp) {
  __shared__ u16 x_lds[16384];
  __shared__ u16 g_lds[16384];
  __shared__ float bt_sh[256], bs_sh[256], bw_sh[256], bf_sh[256];

  int tile = blockIdx.x, b = blockIdx.y;
  int t0 = tile * TT;
  int tid = threadIdx.x, wid = tid >> 6, lane = tid & 63;
  int kb = lens[b] >> (levels[0] - 1);

  if (t0 >= kb) {  // fully masked tile: zero partials only
    if (tid < 256) Sp[(size_t)tile * NROW + b * 256 + tid] = 0.f;
    return;
  }

  if (tid < 256) {
    bt_sh[tid] = btp[tid] * SC_TANH;
    bs_sh[tid] = bsp[tid] * SC_SIGM;
    bw_sh[tid] = bwp[tid] * SC_W;
    bf_sh[tid] = bfp[tid];
  }

  // --- stage x tile (f32 -> bf16, B-frag layout): 8 iterations x 4 rows ---
  const float* xb = x + (size_t)b * Cn * Tn + t0;
  #pragma unroll
  for (int it = 0; it < 8; ++it) {
    int cb = (wid + 8 * it) * 4;                 // c-quad base
    float v0 = __builtin_nontemporal_load(&xb[(size_t)(cb + 0) * Tn + lane]);
    float v1 = __builtin_nontemporal_load(&xb[(size_t)(cb + 1) * Tn + lane]);
    float v2 = __builtin_nontemporal_load(&xb[(size_t)(cb + 2) * Tn + lane]);
    float v3 = __builtin_nontemporal_load(&xb[(size_t)(cb + 3) * Tn + lane]);
    bf16x4v pk = { (__bf16)v0, (__bf16)v1, (__bf16)v2, (__bf16)v3 };
    int frag = ((cb >> 5) * 4 + (lane >> 4));
    int lfr  = ((cb >> 3) & 3) * 16 + (lane & 15);
    *(bf16x4v*)&x_lds[(frag << 9) + (lfr << 3) + (cb & 7)] = pk;
  }
  BAR();

  // --- T,S fused GEMM: tanh/sigm pre-activations (exp2-domain) ---
  f32x4 accT[2][4], accS[2][4];
  #pragma unroll
  for (int j = 0; j < 2; ++j)
    #pragma unroll
    for (int n = 0; n < 4; ++n) { accT[j][n] = (f32x4)0.f; accS[j][n] = (f32x4)0.f; }

  #pragma unroll
  for (int kt = 0; kt < 8; ++kt) {
    bf16x8 bb[4];
    #pragma unroll
    for (int n = 0; n < 4; ++n)
      bb[n] = *(const bf16x8*)&x_lds[((kt * 4 + n) << 9) + (lane << 3)];
    #pragma unroll
    for (int j = 0; j < 2; ++j) {
      int ct = wid * 2 + j;
      bf16x8 at  = *(const bf16x8*)&wtF[(ct * 8 + kt) * 512 + lane * 8];
      bf16x8 as2 = *(const bf16x8*)&wsF[(ct * 8 + kt) * 512 + lane * 8];
      #pragma unroll
      for (int n = 0; n < 4; ++n) {
        accT[j][n] = __builtin_amdgcn_mfma_f32_16x16x32_bf16(at,  bb[n], accT[j][n], 0, 0, 0);
        accS[j][n] = __builtin_amdgcn_mfma_f32_16x16x32_bf16(as2, bb[n], accS[j][n], 0, 0, 0);
      }
    }
  }

  // --- g-epi: g = (1-E1)/((1+E1)(1+E2)), E1=e^{-2v}, E2=e^{-s} -> g_lds ---
  #pragma unroll
  for (int j = 0; j < 2; ++j) {
    int ct = wid * 2 + j;
    int rowbase = ct * 16 + ((lane >> 4) << 2);
    #pragma unroll
    for (int n = 0; n < 4; ++n) {
      bf16x4v pk;
      #pragma unroll
      for (int r = 0; r < 4; ++r) {
        float e1 = EXP2(accT[j][n][r] + bt_sh[rowbase + r]);
        float e2 = EXP2(accS[j][n][r] + bs_sh[rowbase + r]);
        float g = (1.f - e1) * rcpf((1.f + e1) * (1.f + e2));
        pk[r] = (__bf16)g;
      }
      int frag = ((rowbase >> 5) * 4 + n);
      int lfr  = ((rowbase >> 3) & 3) * 16 + (lane & 15);
      *(bf16x4v*)&g_lds[(frag << 9) + (lfr << 3) + (rowbase & 7)] = pk;
    }
  }

  // --- F GEMM (reads x_lds only — independent of g; hides BAR2 skew) ---
  {
    f32x4 accF[2][4];
    #pragma unroll
    for (int j = 0; j < 2; ++j)
      #pragma unroll
      for (int n = 0; n < 4; ++n) accF[j][n] = (f32x4)0.f;
    #pragma unroll
    for (int kt = 0; kt < 8; ++kt) {
      bf16x8 xx[4];
      #pragma unroll
      for (int n = 0; n < 4; ++n)
        xx[n] = *(const bf16x8*)&x_lds[((kt * 4 + n) << 9) + (lane << 3)];
      #pragma unroll
      for (int j = 0; j < 2; ++j) {
        int ct = wid * 2 + j;
        bf16x8 af = *(const bf16x8*)&wfF[(ct * 8 + kt) * 512 + lane * 8];
        #pragma unroll
        for (int n = 0; n < 4; ++n)
          accF[j][n] = __builtin_amdgcn_mfma_f32_16x16x32_bf16(af, xx[n], accF[j][n], 0, 0, 0);
      }
    }
    // F-epi: fv stores (global; not gated by the LDS-only barrier)
    #pragma unroll
    for (int j = 0; j < 2; ++j) {
      int ot = wid * 2 + j;
      int rowbase = ot * 16 + ((lane >> 4) << 2);
      int oq = rowbase >> 2;
      size_t tbase = ((size_t)(b * 64 + oq)) * Tn + t0 + (lane & 15);
      #pragma unroll
      for (int n = 0; n < 4; ++n) {
        bf16x4v ff;
        #pragma unroll
        for (int r = 0; r < 4; ++r)
          ff[r] = (__bf16)(accF[j][n][r] + bf_sh[rowbase + r]);
        *(bf16x4v*)&fW[(tbase + n * 16) * 4] = ff;
      }
    }
  }
  BAR();   // g_lds visible (lgkmcnt covers the ds_writes issued in g-epi)

  // --- Z GEMM: z' = Ww' g + bw' ---
  f32x4 accZ[2][4];
  #pragma unroll
  for (int j = 0; j < 2; ++j)
    #pragma unroll
    for (int n = 0; n < 4; ++n) accZ[j][n] = (f32x4)0.f;

  #pragma unroll
  for (int kt = 0; kt < 8; ++kt) {
    bf16x8 gg[4];
    #pragma unroll
    for (int n = 0; n < 4; ++n)
      gg[n] = *(const bf16x8*)&g_lds[((kt * 4 + n) << 9) + (lane << 3)];
    #pragma unroll
    for (int j = 0; j < 2; ++j) {
      int ct = wid * 2 + j;
      bf16x8 aw = *(const bf16x8*)&wwF[(ct * 8 + kt) * 512 + lane * 8];
      #pragma unroll
      for (int n = 0; n < 4; ++n)
        accZ[j][n] = __builtin_amdgcn_mfma_f32_16x16x32_bf16(aw, gg[n], accZ[j][n], 0, 0, 0);
    }
  }

  // --- Z-epi: p = exp2(z') masked, quad stores, Sp partials ---
  #pragma unroll
  for (int j = 0; j < 2; ++j) {
    int ot = wid * 2 + j;
    int rowbase = ot * 16 + ((lane >> 4) << 2);
    int oq = rowbase >> 2;                      // o-quad index 0..63
    size_t tbase = ((size_t)(b * 64 + oq)) * Tn + t0 + (lane & 15);
    float s[4] = {0.f, 0.f, 0.f, 0.f};
    #pragma unroll
    for (int n = 0; n < 4; ++n) {
      bool v = (t0 + n * 16 + (lane & 15)) < kb;
      bf16x4v pp;
      #pragma unroll
      for (int r = 0; r < 4; ++r) {
        float z = accZ[j][n][r] + bw_sh[rowbase + r];
        float p = v ? EXP2(z) : 0.f;    // |z'| <= ~17: safe
        s[r] += p;
        pp[r] = (__bf16)p;
      }
      *(bf16x4v*)&pW[(tbase + n * 16) * 4] = pp;
    }
    #pragma unroll
    for (int off = 1; off < 16; off <<= 1)
      #pragma unroll
      for (int r = 0; r < 4; ++r) s[r] += __shfl_xor(s[r], off, 64);
    if ((lane & 15) == 0) {
      #pragma unroll
      for (int r = 0; r < 4; ++r)
        Sp[(size_t)tile * NROW + b * 256 + rowbase + r] = s[r];
    }
  }
}

// ---------------------------------------------------------------------------
// Pass 2: one block per (b, o-quad). a = p/D, a2 = a*fv, out = sum a2.
// ---------------------------------------------------------------------------
__global__ __launch_bounds__(256) void pass2_k(
    const int* __restrict__ lens, const int* __restrict__ levels,
    const u16* __restrict__ pW, const u16* __restrict__ fW,
    const float* __restrict__ Sp,
    float* __restrict__ out0, float* __restrict__ aOut, float* __restrict__ a2Out) {
  int b = blockIdx.y, oq = blockIdx.x;
  int kb = lens[b] >> (levels[0] - 1);
  int tid = threadIdx.x, wid = tid >> 6, lane = tid & 63;
  __shared__ float dsh[16];
  __shared__ float obuf[16];

  // D for the 4 rows: tid -> (tile = tid>>2, r = tid&3)
  float v = Sp[(size_t)(tid >> 2) * NROW + b * 256 + oq * 4 + (tid & 3)];
  #pragma unroll
  for (int off = 4; off < 64; off <<= 1) v += __shfl_xor(v, off, 64);
  if (lane < 4) dsh[wid * 4 + lane] = v;
  __syncthreads();
  float scr[4];
  #pragma unroll
  for (int r = 0; r < 4; ++r)
    scr[r] = 1.f / (dsh[r] + dsh[4 + r] + dsh[8 + r] + dsh[12 + r]);

  size_t pbase = ((size_t)(b * 64 + oq)) * Tn;        // in t units; elem idx = (pbase+t)*4
  size_t obase0 = ((size_t)(b * 256 + oq * 4)) * Tn;  // row 0 of the quad
  float osum[4] = {0.f, 0.f, 0.f, 0.f};

  #pragma unroll
  for (int c = 0; c < 4; ++c) {
    int t = c * 1024 + tid * 4;
    if (t < kb) {
      u16x8 pa = *(const u16x8*)&pW[(pbase + t) * 4];      // t, t+1
      u16x8 pb = *(const u16x8*)&pW[(pbase + t) * 4 + 8];  // t+2, t+3
      u16x8 fa = *(const u16x8*)&fW[(pbase + t) * 4];
      u16x8 fb = *(const u16x8*)&fW[(pbase + t) * 4 + 8];
      bool v1 = (t + 1) < kb, v2 = (t + 2) < kb, v3 = (t + 3) < kb;
      #pragma unroll
      for (int r = 0; r < 4; ++r) {
        float a0 = bf2f(pa[r]) * scr[r];
        float a1 = v1 ? bf2f(pa[4 + r]) * scr[r] : 0.f;
        float a2_ = v2 ? bf2f(pb[r]) * scr[r] : 0.f;
        float a3 = v3 ? bf2f(pb[4 + r]) * scr[r] : 0.f;
        f32x4 av = { a0, a1, a2_, a3 };
        f32x4 a2v = { a0 * bf2f(fa[r]), a1 * bf2f(fa[4 + r]),
                      a2_ * bf2f(fb[r]), a3 * bf2f(fb[4 + r]) };
        osum[r] += a2v[0] + a2v[1] + a2v[2] + a2v[3];
        __builtin_nontemporal_store(av,  (f32x4*)&aOut[obase0 + (size_t)r * Tn + t]);
        __builtin_nontemporal_store(a2v, (f32x4*)&a2Out[obase0 + (size_t)r * Tn + t]);
      }
    } else {
      f32x4 z4 = (f32x4)0.f;
      #pragma unroll
      for (int r = 0; r < 4; ++r) {
        __builtin_nontemporal_store(z4, (f32x4*)&aOut[obase0 + (size_t)r * Tn + t]);
        __builtin_nontemporal_store(z4, (f32x4*)&a2Out[obase0 + (size_t)r * Tn + t]);
      }
    }
  }

  // out0: per-wave shuffle reduce each row, then cross-wave via LDS
  #pragma unroll
  for (int r = 0; r < 4; ++r) {
    float s = osum[r];
    #pragma unroll
    for (int off = 1; off < 64; off <<= 1) s += __shfl_xor(s, off, 64);
    if (lane == 0) obuf[wid * 4 + r] = s;
  }
  __syncthreads();
  if (tid < 4)
    out0[b * 256 + oq * 4 + tid] = obuf[tid] + obuf[4 + tid] + obuf[8 + tid] + obuf[12 + tid];
}

// ---------------------------------------------------------------------------
extern "C" void kernel_launch(void* const* d_in, const int* in_sizes, int n_in,
                              void* d_out, int out_size, void* d_ws, size_t ws_size,
                              hipStream_t stream) {
  const float* x    = (const float*)d_in[0];
  const int*   lens = (const int*)d_in[1];
  const int*   lev  = (const int*)d_in[2];
  const float* Wt = (const float*)d_in[3];
  const float* bt = (const float*)d_in[4];
  const float* Ws = (const float*)d_in[5];
  const float* bs = (const float*)d_in[6];
  const float* Ww = (const float*)d_in[7];
  const float* bw = (const float*)d_in[8];
  const float* Wf = (const float*)d_in[9];
  const float* bf = (const float*)d_in[10];

  u16* wsu = (u16*)d_ws;
  u16* wtF = wsu;                 // 4 x 65536 u16 = 512 KB
  u16* wsF = wsu + 65536;
  u16* wwF = wsu + 131072;
  u16* wfF = wsu + 196608;
  u16* pW  = wsu + 262144;        // [b][oq][t][4] bf16 = 134 MB
  u16* fW  = pW + (size_t)NROW * Tn;
  float* Sp = (float*)(fW + (size_t)NROW * Tn);  // [NTILE][NROW] = 4 MB

  float* out0  = (float*)d_out;
  float* aOut  = out0 + Bn * On;
  float* a2Out = aOut + (size_t)Bn * On * Tn;

  wprep_k<<<1024, 256, 0, stream>>>(Wt, Ws, Ww, Wf, wsu);
  pass1_k<<<dim3(NTILE, Bn), 512, 0, stream>>>(x, lens, lev, wtF, wsF, wwF, wfF,
                                               bt, bs, bw, bf, pW, fW, Sp);
  pass2_k<<<dim3(64, Bn), 256, 0, stream>>>(lens, lev, pW, fW, Sp, out0, aOut, a2Out);
}

// Round 7
// 229.546 us; speedup vs baseline: 3.6467x; 1.1264x over previous
//
#include <hip/hip_runtime.h>
#include <math.h>

// Problem constants
#define Bn 64
#define Cn 256
#define Tn 4096
#define On 256
#define TT 64        // t-tile per block
#define NTILE 64     // Tn/TT
#define NROW 16384   // Bn*On

typedef float f32x4 __attribute__((ext_vector_type(4)));
typedef __bf16 bf16x8 __attribute__((ext_vector_type(8)));
typedef __bf16 bf16x4v __attribute__((ext_vector_type(4)));
typedef unsigned short u16;
typedef u16 u16x8 __attribute__((ext_vector_type(8)));

static __device__ __forceinline__ float rcpf(float x) { return __builtin_amdgcn_rcpf(x); }
static __device__ __forceinline__ float bf2f(u16 u) { return __uint_as_float(((unsigned)u) << 16); }

#if __has_builtin(__builtin_amdgcn_exp2f)
#define EXP2(x) __builtin_amdgcn_exp2f(x)
#else
#define EXP2(x) exp2f(x)
#endif

// LDS-only barrier: no vmcnt(0) drain.
#define BAR() do { asm volatile("s_waitcnt lgkmcnt(0)" ::: "memory"); \
                   __builtin_amdgcn_s_barrier(); } while (0)

// log2(e) folding scales
#define SC_TANH -2.8853900817779268f   // -2*log2(e): E1 = exp2(Wt'x+bt') = e^{-2v}
#define SC_SIGM -1.4426950408889634f   // -log2(e):   E2 = e^{-s}
#define SC_W     1.4426950408889634f   // +log2(e):   p  = exp2(z') = e^{z}

// ---------------------------------------------------------------------------
// Kernel 0: weights f32 -> bf16, A-fragment order, with exp2 folding scales.
// ---------------------------------------------------------------------------
__global__ void wprep_k(const float* __restrict__ Wt, const float* __restrict__ Ws,
                        const float* __restrict__ Ww, const float* __restrict__ Wf,
                        u16* __restrict__ dst) {
  int gid = blockIdx.x * 256 + threadIdx.x;     // 0 .. 4*65536-1
  int w = gid >> 16, rem = gid & 65535;
  int frag = rem >> 9, lane = (rem >> 3) & 63, i = rem & 7;
  int ot = frag >> 3, kt = frag & 7;
  int row = ot * 16 + (lane & 15);
  int col = kt * 32 + ((lane >> 4) << 3) + i;
  const float* W = (w == 0) ? Wt : (w == 1) ? Ws : (w == 2) ? Ww : Wf;
  float sc = (w == 0) ? SC_TANH : (w == 1) ? SC_SIGM : (w == 2) ? SC_W : 1.0f;
  __bf16 h = (__bf16)(W[row * 256 + col] * sc);
  dst[gid] = *(u16*)&h;
}

// ---------------------------------------------------------------------------
// Pass 1 (verified R2 structure): stage x -> BAR -> [T,S GEMM] -> g-epi ->
// BAR -> [Z,F fused GEMM] -> epilogues. 8 waves x 2 o-tiles, 68 KB LDS ->
// 2 blocks/CU, 4 waves/SIMD (VGPR-capped). s_setprio(1) wraps the MFMA
// clusters (T5): with 2 independent blocks/CU at different phases, MFMA-
// entering waves get scheduler preference over staging/ds_read waves.
// ---------------------------------------------------------------------------
__global__ __launch_bounds__(512, 4) void pass1_k(
    const float* __restrict__ x, const int* __restrict__ lens, const int* __restrict__ levels,
    const u16* __restrict__ wtF, const u16* __restrict__ wsF, const u16* __restrict__ wwF,
    const u16* __restrict__ wfF,
    const float* __restrict__ btp, const float* __restrict__ bsp, const float* __restrict__ bwp,
    const float* __restrict__ bfp,
    u16* __restrict__ pW, u16* __restrict__ fW,
    float* __restrict__ Sp) {
  __shared__ u16 x_lds[16384];
  __shared__ u16 g_lds[16384];
  __shared__ float bt_sh[256], bs_sh[256], bw_sh[256], bf_sh[256];

  int tile = blockIdx.x, b = blockIdx.y;
  int t0 = tile * TT;
  int tid = threadIdx.x, wid = tid >> 6, lane = tid & 63;
  int kb = lens[b] >> (levels[0] - 1);

  if (t0 >= kb) {  // fully masked tile: zero partials only
    if (tid < 256) Sp[(size_t)tile * NROW + b * 256 + tid] = 0.f;
    return;
  }

  if (tid < 256) {
    bt_sh[tid] = btp[tid] * SC_TANH;
    bs_sh[tid] = bsp[tid] * SC_SIGM;
    bw_sh[tid] = bwp[tid] * SC_W;
    bf_sh[tid] = bfp[tid];
  }

  // --- stage x tile (f32 -> bf16, B-frag layout): 8 iterations x 4 rows ---
  const float* xb = x + (size_t)b * Cn * Tn + t0;
  #pragma unroll
  for (int it = 0; it < 8; ++it) {
    int cb = (wid + 8 * it) * 4;                 // c-quad base
    float v0 = __builtin_nontemporal_load(&xb[(size_t)(cb + 0) * Tn + lane]);
    float v1 = __builtin_nontemporal_load(&xb[(size_t)(cb + 1) * Tn + lane]);
    float v2 = __builtin_nontemporal_load(&xb[(size_t)(cb + 2) * Tn + lane]);
    float v3 = __builtin_nontemporal_load(&xb[(size_t)(cb + 3) * Tn + lane]);
    bf16x4v pk = { (__bf16)v0, (__bf16)v1, (__bf16)v2, (__bf16)v3 };
    int frag = ((cb >> 5) * 4 + (lane >> 4));
    int lfr  = ((cb >> 3) & 3) * 16 + (lane & 15);
    *(bf16x4v*)&x_lds[(frag << 9) + (lfr << 3) + (cb & 7)] = pk;
  }
  BAR();

  // --- GEMM phase A: tanh/sigm pre-activations (exp2-domain) ---
  f32x4 accT[2][4], accS[2][4];
  #pragma unroll
  for (int j = 0; j < 2; ++j)
    #pragma unroll
    for (int n = 0; n < 4; ++n) { accT[j][n] = (f32x4)0.f; accS[j][n] = (f32x4)0.f; }

  #pragma unroll
  for (int kt = 0; kt < 8; ++kt) {
    bf16x8 bb[4];
    #pragma unroll
    for (int n = 0; n < 4; ++n)
      bb[n] = *(const bf16x8*)&x_lds[((kt * 4 + n) << 9) + (lane << 3)];
    #pragma unroll
    for (int j = 0; j < 2; ++j) {
      int ct = wid * 2 + j;
      bf16x8 at  = *(const bf16x8*)&wtF[(ct * 8 + kt) * 512 + lane * 8];
      bf16x8 as2 = *(const bf16x8*)&wsF[(ct * 8 + kt) * 512 + lane * 8];
      __builtin_amdgcn_s_setprio(1);
      #pragma unroll
      for (int n = 0; n < 4; ++n) {
        accT[j][n] = __builtin_amdgcn_mfma_f32_16x16x32_bf16(at,  bb[n], accT[j][n], 0, 0, 0);
        accS[j][n] = __builtin_amdgcn_mfma_f32_16x16x32_bf16(as2, bb[n], accS[j][n], 0, 0, 0);
      }
      __builtin_amdgcn_s_setprio(0);
    }
  }

  // activation epilogue: g = (1-E1) / ((1+E1)(1+E2)), E1=e^{-2v}, E2=e^{-s}
  #pragma unroll
  for (int j = 0; j < 2; ++j) {
    int ct = wid * 2 + j;
    int rowbase = ct * 16 + ((lane >> 4) << 2);
    #pragma unroll
    for (int n = 0; n < 4; ++n) {
      bf16x4v pk;
      #pragma unroll
      for (int r = 0; r < 4; ++r) {
        float e1 = EXP2(accT[j][n][r] + bt_sh[rowbase + r]);
        float e2 = EXP2(accS[j][n][r] + bs_sh[rowbase + r]);
        float g = (1.f - e1) * rcpf((1.f + e1) * (1.f + e2));
        pk[r] = (__bf16)g;
      }
      int frag = ((rowbase >> 5) * 4 + n);
      int lfr  = ((rowbase >> 3) & 3) * 16 + (lane & 15);
      *(bf16x4v*)&g_lds[(frag << 9) + (lfr << 3) + (rowbase & 7)] = pk;
    }
  }
  BAR();

  // --- GEMM phase B: z' = Ww' g + bw' ; fv = Wf x + bf ---
  f32x4 accZ[2][4], accF[2][4];
  #pragma unroll
  for (int j = 0; j < 2; ++j)
    #pragma unroll
    for (int n = 0; n < 4; ++n) { accZ[j][n] = (f32x4)0.f; accF[j][n] = (f32x4)0.f; }

  #pragma unroll
  for (int kt = 0; kt < 8; ++kt) {
    bf16x8 gg[4], xx[4];
    #pragma unroll
    for (int n = 0; n < 4; ++n) {
      gg[n] = *(const bf16x8*)&g_lds[((kt * 4 + n) << 9) + (lane << 3)];
      xx[n] = *(const bf16x8*)&x_lds[((kt * 4 + n) << 9) + (lane << 3)];
    }
    #pragma unroll
    for (int j = 0; j < 2; ++j) {
      int ct = wid * 2 + j;
      bf16x8 aw = *(const bf16x8*)&wwF[(ct * 8 + kt) * 512 + lane * 8];
      bf16x8 af = *(const bf16x8*)&wfF[(ct * 8 + kt) * 512 + lane * 8];
      __builtin_amdgcn_s_setprio(1);
      #pragma unroll
      for (int n = 0; n < 4; ++n) {
        accZ[j][n] = __builtin_amdgcn_mfma_f32_16x16x32_bf16(aw, gg[n], accZ[j][n], 0, 0, 0);
        accF[j][n] = __builtin_amdgcn_mfma_f32_16x16x32_bf16(af, xx[n], accF[j][n], 0, 0, 0);
      }
      __builtin_amdgcn_s_setprio(0);
    }
  }

  // --- epilogue: p = exp2(z') (masked), tile-sum partial; direct quad stores ---
  #pragma unroll
  for (int j = 0; j < 2; ++j) {
    int ot = wid * 2 + j;
    int rowbase = ot * 16 + ((lane >> 4) << 2);
    int oq = rowbase >> 2;                      // o-quad index 0..63
    size_t tbase = ((size_t)(b * 64 + oq)) * Tn + t0 + (lane & 15);
    float s[4] = {0.f, 0.f, 0.f, 0.f};
    #pragma unroll
    for (int n = 0; n < 4; ++n) {
      bool v = (t0 + n * 16 + (lane & 15)) < kb;
      bf16x4v pp, ff;
      #pragma unroll
      for (int r = 0; r < 4; ++r) {
        float z = accZ[j][n][r] + bw_sh[rowbase + r];
        float p = v ? EXP2(z) : 0.f;    // |z'| <= ~17: safe
        s[r] += p;
        pp[r] = (__bf16)p;
        ff[r] = (__bf16)(accF[j][n][r] + bf_sh[rowbase + r]);
      }
      *(bf16x4v*)&pW[(tbase + n * 16) * 4] = pp;
      *(bf16x4v*)&fW[(tbase + n * 16) * 4] = ff;
    }
    #pragma unroll
    for (int off = 1; off < 16; off <<= 1)
      #pragma unroll
      for (int r = 0; r < 4; ++r) s[r] += __shfl_xor(s[r], off, 64);
    if ((lane & 15) == 0) {
      #pragma unroll
      for (int r = 0; r < 4; ++r)
        Sp[(size_t)tile * NROW + b * 256 + rowbase + r] = s[r];
    }
  }
}

// ---------------------------------------------------------------------------
// Pass 2: one block per (b, o-quad). a = p/D, a2 = a*fv, out = sum a2.
// ---------------------------------------------------------------------------
__global__ __launch_bounds__(256) void pass2_k(
    const int* __restrict__ lens, const int* __restrict__ levels,
    const u16* __restrict__ pW, const u16* __restrict__ fW,
    const float* __restrict__ Sp,
    float* __restrict__ out0, float* __restrict__ aOut, float* __restrict__ a2Out) {
  int b = blockIdx.y, oq = blockIdx.x;
  int kb = lens[b] >> (levels[0] - 1);
  int tid = threadIdx.x, wid = tid >> 6, lane = tid & 63;
  __shared__ float dsh[16];
  __shared__ float obuf[16];

  // D for the 4 rows: tid -> (tile = tid>>2, r = tid&3)
  float v = Sp[(size_t)(tid >> 2) * NROW + b * 256 + oq * 4 + (tid & 3)];
  #pragma unroll
  for (int off = 4; off < 64; off <<= 1) v += __shfl_xor(v, off, 64);
  if (lane < 4) dsh[wid * 4 + lane] = v;
  __syncthreads();
  float scr[4];
  #pragma unroll
  for (int r = 0; r < 4; ++r)
    scr[r] = 1.f / (dsh[r] + dsh[4 + r] + dsh[8 + r] + dsh[12 + r]);

  size_t pbase = ((size_t)(b * 64 + oq)) * Tn;        // in t units; elem idx = (pbase+t)*4
  size_t obase0 = ((size_t)(b * 256 + oq * 4)) * Tn;  // row 0 of the quad
  float osum[4] = {0.f, 0.f, 0.f, 0.f};

  #pragma unroll
  for (int c = 0; c < 4; ++c) {
    int t = c * 1024 + tid * 4;
    if (t < kb) {
      // plain loads: let the tail of pass1's p/f writes hit L2/L3
      u16x8 pa = *(const u16x8*)&pW[(pbase + t) * 4];      // t, t+1
      u16x8 pb = *(const u16x8*)&pW[(pbase + t) * 4 + 8];  // t+2, t+3
      u16x8 fa = *(const u16x8*)&fW[(pbase + t) * 4];
      u16x8 fb = *(const u16x8*)&fW[(pbase + t) * 4 + 8];
      bool v1 = (t + 1) < kb, v2 = (t + 2) < kb, v3 = (t + 3) < kb;
      #pragma unroll
      for (int r = 0; r < 4; ++r) {
        float a0 = bf2f(pa[r]) * scr[r];
        float a1 = v1 ? bf2f(pa[4 + r]) * scr[r] : 0.f;
        float a2_ = v2 ? bf2f(pb[r]) * scr[r] : 0.f;
        float a3 = v3 ? bf2f(pb[4 + r]) * scr[r] : 0.f;
        f32x4 av = { a0, a1, a2_, a3 };
        f32x4 a2v = { a0 * bf2f(fa[r]), a1 * bf2f(fa[4 + r]),
                      a2_ * bf2f(fb[r]), a3 * bf2f(fb[4 + r]) };
        osum[r] += a2v[0] + a2v[1] + a2v[2] + a2v[3];
        __builtin_nontemporal_store(av,  (f32x4*)&aOut[obase0 + (size_t)r * Tn + t]);
        __builtin_nontemporal_store(a2v, (f32x4*)&a2Out[obase0 + (size_t)r * Tn + t]);
      }
    } else {
      f32x4 z4 = (f32x4)0.f;
      #pragma unroll
      for (int r = 0; r < 4; ++r) {
        __builtin_nontemporal_store(z4, (f32x4*)&aOut[obase0 + (size_t)r * Tn + t]);
        __builtin_nontemporal_store(z4, (f32x4*)&a2Out[obase0 + (size_t)r * Tn + t]);
      }
    }
  }

  // out0: per-wave shuffle reduce each row, then cross-wave via LDS
  #pragma unroll
  for (int r = 0; r < 4; ++r) {
    float s = osum[r];
    #pragma unroll
    for (int off = 1; off < 64; off <<= 1) s += __shfl_xor(s, off, 64);
    if (lane == 0) obuf[wid * 4 + r] = s;
  }
  __syncthreads();
  if (tid < 4)
    out0[b * 256 + oq * 4 + tid] = obuf[tid] + obuf[4 + tid] + obuf[8 + tid] + obuf[12 + tid];
}

// ---------------------------------------------------------------------------
extern "C" void kernel_launch(void* const* d_in, const int* in_sizes, int n_in,
                              void* d_out, int out_size, void* d_ws, size_t ws_size,
                              hipStream_t stream) {
  const float* x    = (const float*)d_in[0];
  const int*   lens = (const int*)d_in[1];
  const int*   lev  = (const int*)d_in[2];
  const float* Wt = (const float*)d_in[3];
  const float* bt = (const float*)d_in[4];
  const float* Ws = (const float*)d_in[5];
  const float* bs = (const float*)d_in[6];
  const float* Ww = (const float*)d_in[7];
  const float* bw = (const float*)d_in[8];
  const float* Wf = (const float*)d_in[9];
  const float* bf = (const float*)d_in[10];

  u16* wsu = (u16*)d_ws;
  u16* wtF = wsu;                 // 4 x 65536 u16 = 512 KB
  u16* wsF = wsu + 65536;
  u16* wwF = wsu + 131072;
  u16* wfF = wsu + 196608;
  u16* pW  = wsu + 262144;        // [b][oq][t][4] bf16 = 134 MB
  u16* fW  = pW + (size_t)NROW * Tn;
  float* Sp = (float*)(fW + (size_t)NROW * Tn);  // [NTILE][NROW] = 4 MB

  float* out0  = (float*)d_out;
  float* aOut  = out0 + Bn * On;
  float* a2Out = aOut + (size_t)Bn * On * Tn;

  wprep_k<<<1024, 256, 0, stream>>>(Wt, Ws, Ww, Wf, wsu);
  pass1_k<<<dim3(NTILE, Bn), 512, 0, stream>>>(x, lens, lev, wtF, wsF, wwF, wfF,
                                               bt, bs, bw, bf, pW, fW, Sp);
  pass2_k<<<dim3(64, Bn), 256, 0, stream>>>(lens, lev, pW, fW, Sp, out0, aOut, a2Out);
}